// Round 3
// baseline (63158.429 us; speedup 1.0000x reference)
//
#include <hip/hip_runtime.h>
#include <hip/hip_cooperative_groups.h>
#include <cstdint>
#include <cstddef>

namespace cg = cooperative_groups;

#define L2E 1.4426950408889634f

typedef __attribute__((ext_vector_type(8))) short short8v;
typedef __attribute__((ext_vector_type(4))) float f32x4;

__device__ __forceinline__ float fexp2(float x){ return __builtin_amdgcn_exp2f(x); }
__device__ __forceinline__ float frcp(float x){ return __builtin_amdgcn_rcpf(x); }
__device__ __forceinline__ float tanh_f(float x){
  return 1.f - 2.f*frcp(1.f + fexp2(2.f*L2E*x));
}
__device__ __forceinline__ float sigm_f(float x){
  return frcp(1.f + fexp2(-L2E*x));
}
__device__ __forceinline__ float bf2f(ushort u){ return __uint_as_float(((uint32_t)u)<<16); }
__device__ __forceinline__ ushort f2bf(float f){
  uint32_t x = __float_as_uint(f);
  uint32_t r = (x + 0x7FFFu + ((x>>16)&1u)) >> 16;
  return (ushort)r;
}

namespace {
constexpr int NB = 32, TT = 512, DD = 768, HH = 512;
// byte offsets into ws
constexpr size_t EPB  = 0;                               // ep bf16 [B][H][T]
constexpr size_t XBB  = EPB  + (size_t)NB*HH*TT*2;       // x bf16 [B][T][D]
constexpr size_t HSB  = XBB  + (size_t)NB*TT*DD*2;       // hs bf16 [2][T][B][H]
constexpr size_t WPKB = HSB  + (size_t)2*TT*NB*HH*2;     // Wpack bf16 [2][128][64][64][8]
constexpr size_t WDPB = WPKB + (size_t)2*128*64*64*8*2;  // Wdec pack bf16 [32][16][64][8]
constexpr size_t UCTXB= WDPB + (size_t)32*16*64*8*2;     // uctx f32 [2][B][D]
constexpr size_t ZBB  = UCTXB+ (size_t)2*NB*DD*4;        // Z f32 [2][B]
constexpr size_t DECB = ZBB  + (size_t)2*NB*4;           // dec f32 [2][B][H]
constexpr size_t CSTB = DECB + (size_t)2*NB*HH*4;        // c f32 [2][B][H]
constexpr size_t WS_BYTES = CSTB + (size_t)2*NB*HH*4;
}

// ---------------- x -> bf16
__global__ void k_xcast(const float* __restrict__ x, ushort* __restrict__ xb)
{
  size_t i = ((size_t)blockIdx.x*256 + threadIdx.x)*8;
  float4 v0 = *(const float4*)(x + i);
  float4 v1 = *(const float4*)(x + i + 4);
  short8v o;
  o[0]=(short)f2bf(v0.x); o[1]=(short)f2bf(v0.y); o[2]=(short)f2bf(v0.z); o[3]=(short)f2bf(v0.w);
  o[4]=(short)f2bf(v1.x); o[5]=(short)f2bf(v1.y); o[6]=(short)f2bf(v1.z); o[7]=(short)f2bf(v1.w);
  *(short8v*)(xb + i) = o;
}

// ---------------- enc projection: ep[b][h][t] = x[b][t][:]·Wenc[h][:] + benc[h]
__global__ void k_encproj(const float* __restrict__ x, const float* __restrict__ Wenc,
                          const float* __restrict__ benc, ushort* __restrict__ epT)
{
  int b = blockIdx.z, h0 = blockIdx.y*64, t0 = blockIdx.x*64;
  __shared__ float As[64][33];
  __shared__ float Bs[64][33];
  int tid = threadIdx.x;
  int n = tid & 63, mg = tid >> 6;
  float acc[16];
  #pragma unroll
  for (int j = 0; j < 16; j++) acc[j] = 0.f;
  int lr = tid >> 2, lk = (tid & 3) * 8;
  for (int k0 = 0; k0 < 768; k0 += 32) {
    const float* ap = Wenc + (size_t)(h0 + lr)*768 + k0 + lk;
    #pragma unroll
    for (int i = 0; i < 8; i++) As[lr][lk + i] = ap[i];
    const float* bp = x + ((size_t)b*512 + t0 + lr)*768 + k0 + lk;
    #pragma unroll
    for (int i = 0; i < 8; i++) Bs[lr][lk + i] = bp[i];
    __syncthreads();
    #pragma unroll
    for (int kk = 0; kk < 32; kk++) {
      float bv = Bs[n][kk];
      #pragma unroll
      for (int j = 0; j < 16; j++) acc[j] += As[mg*16 + j][kk] * bv;
    }
    __syncthreads();
  }
  #pragma unroll
  for (int j = 0; j < 16; j++) {
    int h = h0 + mg*16 + j;
    epT[((size_t)b*512 + h)*512 + t0 + n] = f2bf(acc[j] + benc[h]);
  }
}

// ---------------- pre-pack gate weights into MFMA fragment order
__global__ void k_wpack(const float* __restrict__ Wfih, const float* __restrict__ Wfhh,
                        const float* __restrict__ Wbih, const float* __restrict__ Wbhh,
                        ushort* __restrict__ wpk)
{
  size_t f = (size_t)blockIdx.x*256 + threadIdx.x;   // 1,048,576 total
  int lane = (int)(f & 63), kstep = (int)((f>>6)&63), jblk = (int)((f>>12)&127), dir = (int)(f>>19);
  const float* Whh = dir ? Wbhh : Wfhh;
  const float* Wih = dir ? Wbih : Wfih;
  int c = lane & 15, gate = c >> 2, jj = c & 3;
  int row = gate*512 + jblk*4 + jj;
  int kbase = kstep*32 + (lane>>4)*8;
  short8v o;
  #pragma unroll
  for (int i = 0; i < 8; i++) {
    int k = kbase + i;
    float w = (k < 512) ? Whh[(size_t)row*512 + k] : Wih[(size_t)row*1536 + (k - 512)];
    o[i] = (short)f2bf(w);
  }
  *(short8v*)(wpk + f*8) = o;
}

// ---------------- pre-pack Wdec into MFMA B-fragment order [nb32][kstep16][lane64][8]
__global__ void k_wdpack(const float* __restrict__ Wdec, ushort* __restrict__ wdp)
{
  int f = blockIdx.x*256 + threadIdx.x;   // 32768 total
  int lane = f & 63, kstep = (f >> 6) & 15, nb = f >> 10;
  int n = nb*16 + (lane & 15);
  int kbase = kstep*32 + (lane >> 4)*8;
  short8v o;
  #pragma unroll
  for (int i = 0; i < 8; i++) o[i] = (short)f2bf(Wdec[(size_t)n*512 + kbase + i]);
  *(short8v*)(wdp + (size_t)f*8) = o;
}

// ---------------- persistent cooperative loop: 512 steps, 3 phases per step
__global__ __launch_bounds__(512, 2) void k_loop(
    ushort* __restrict__ hsb, const ushort* __restrict__ xb, const ushort* __restrict__ ep,
    const ushort* __restrict__ wpk, const ushort* __restrict__ wdp,
    float* __restrict__ uctx, float* __restrict__ Zb, float* __restrict__ dec,
    float* __restrict__ cst, const float* __restrict__ bdec, const float* __restrict__ vg,
    const float* __restrict__ bfv, const float* __restrict__ bbv)
{
  cg::grid_group grid = cg::this_grid();
  __shared__ __align__(16) char smem[32768];
  const int bid = blockIdx.x;
  const int tid = threadIdx.x;
  const int wid = tid >> 6, lane = tid & 63;
  const int l15 = lane & 15, lk8 = (lane >> 4) * 8;

  for (int s = 0; s < TT; ++s) {
    // ======== phase D: dec = h_prev·Wdec^T + bdec (blocks 0..31, MFMA) ; zero uctx/Z (32..63)
    if (bid < 32) {
      int nb = bid;
      if (s == 0) {
        for (int e = tid; e < 1024; e += 512) {
          int row = e >> 4, col = e & 15;
          int m = row >> 4, rl = row & 15;
          int dir = m >> 1, b = (m & 1)*16 + rl;
          dec[((size_t)dir*32 + b)*512 + nb*16 + col] = bdec[nb*16 + col];
        }
      } else {
        float (*redD)[64][16] = (float(*)[64][16])smem;
        f32x4 acc[4] = {{0,0,0,0},{0,0,0,0},{0,0,0,0},{0,0,0,0}};
        int tp0 = s - 1, tp1 = 512 - s;
        #pragma unroll
        for (int kk = 0; kk < 2; kk++) {
          int kstep = wid*2 + kk;
          int ko = kstep*32 + lk8;
          short8v bv = *(const short8v*)(wdp + (((size_t)nb*16 + kstep)*64 + lane)*8);
          #pragma unroll
          for (int m = 0; m < 4; m++) {
            int dir = m >> 1, brow = (m & 1)*16 + l15;
            int tp = dir ? tp1 : tp0;
            const ushort* hp = hsb + (((size_t)dir*512 + tp)*32 + brow)*512 + ko;
            short8v av = *(const short8v*)hp;
            acc[m] = __builtin_amdgcn_mfma_f32_16x16x32_bf16(av, bv, acc[m], 0, 0, 0);
          }
        }
        #pragma unroll
        for (int m = 0; m < 4; m++)
          #pragma unroll
          for (int r = 0; r < 4; r++)
            redD[wid][m*16 + (lane>>4)*4 + r][l15] = acc[m][r];
        __syncthreads();
        for (int e = tid; e < 1024; e += 512) {
          int row = e >> 4, col = e & 15;
          float dv = 0.f;
          #pragma unroll
          for (int w = 0; w < 8; w++) dv += redD[w][row][col];
          int m = row >> 4, rl = row & 15;
          int dir = m >> 1, b = (m & 1)*16 + rl;
          dec[((size_t)dir*32 + b)*512 + nb*16 + col] = dv + bdec[nb*16 + col];
        }
      }
    } else if (bid < 64) {
      int base = (bid - 32)*512 + tid;
      for (int i = base; i < 2*32*768; i += 16384) uctx[i] = 0.f;
      if (base < 64) Zb[base] = 0.f;
    }
    grid.sync();

    // ======== phase S: scores + shifted exp + unnormalized ctx (all 256 blocks)
    {
      float* sf = (float*)smem;
      float* d0 = sf; float* d1 = sf + 512; float* vsm = sf + 1024;
      float (*scr)[8][64] = (float(*)[8][64])(sf + 1536);
      float (*ev)[64] = (float(*)[64])(sf + 2560);
      int b = bid >> 3, tc = bid & 7, t0 = tc*64;
      d0[tid] = dec[(size_t)b*512 + tid];
      d1[tid] = dec[((size_t)32 + b)*512 + tid];
      vsm[tid] = vg[tid];
      __syncthreads();
      int tl = tid & 63, hg = tid >> 6;
      const ushort* epp = ep + ((size_t)b*512 + hg*64)*512 + t0 + tl;
      float s0 = 0.f, s1 = 0.f;
      #pragma unroll 8
      for (int hh = 0; hh < 64; hh++) {
        int h = hg*64 + hh;
        float e = bf2f(*epp); epp += 512;
        s0 += tanh_f(e + d0[h]) * vsm[h];
        s1 += tanh_f(e + d1[h]) * vsm[h];
      }
      scr[0][hg][tl] = s0; scr[1][hg][tl] = s1;
      __syncthreads();
      if (tid < 128) {
        int dq = tid >> 6, tq = tid & 63;
        float sv = 0.f;
        #pragma unroll
        for (int g = 0; g < 8; g++) sv += scr[dq][g][tq];
        sv = fminf(sv, 100.f);
        float e = fexp2((sv - 32.f)*L2E);
        ev[dq][tq] = e;
        float z = e;
        #pragma unroll
        for (int off = 32; off; off >>= 1) z += __shfl_xor(z, off);
        if (tq == 0) atomicAdd(Zb + dq*32 + b, z);
      }
      __syncthreads();
      for (int dd = tid; dd < 768; dd += 512) {
        const ushort* xp = xb + ((size_t)b*512 + t0)*768 + dd;
        float a0 = 0.f, a1 = 0.f;
        #pragma unroll 8
        for (int t = 0; t < 64; t++) {
          float xv = bf2f(xp[(size_t)t*768]);
          a0 += ev[0][t]*xv;
          a1 += ev[1][t]*xv;
        }
        atomicAdd(uctx + (size_t)b*768 + dd, a0);
        atomicAdd(uctx + ((size_t)32 + b)*768 + dd, a1);
      }
    }
    grid.sync();

    // ======== phase G: gates MFMA GEMM (K=2048 = h|ctx|x) + fused LSTM pointwise
    {
      float (*red)[32][16] = (float(*)[32][16])smem;
      float (*gfin)[17] = (float(*)[17])(smem + 16384);
      int dir = bid >> 7, jblk = bid & 127;
      int t_in = dir ? (511 - s) : s;
      int b0 = l15, b1 = 16 + l15;
      f32x4 acc0 = {0,0,0,0}, acc1 = {0,0,0,0};
      const ushort* wpb = wpk + (((size_t)dir*128 + jblk)*64)*512;

      if (wid < 2) {                       // ksteps 0..15 : h_prev part
        if (s > 0) {
          int t_prev = dir ? (512 - s) : (s - 1);
          const ushort* h0 = hsb + (((size_t)dir*512 + t_prev)*32 + b0)*512;
          const ushort* h1 = hsb + (((size_t)dir*512 + t_prev)*32 + b1)*512;
          #pragma unroll
          for (int kk = 0; kk < 8; kk++) {
            int kstep = wid*8 + kk;
            int ko = kstep*32 + lk8;
            short8v a0v = *(const short8v*)(h0 + ko);
            short8v a1v = *(const short8v*)(h1 + ko);
            short8v bv  = *(const short8v*)(wpb + (size_t)kstep*512 + lane*8);
            acc0 = __builtin_amdgcn_mfma_f32_16x16x32_bf16(a0v, bv, acc0, 0, 0, 0);
            acc1 = __builtin_amdgcn_mfma_f32_16x16x32_bf16(a1v, bv, acc1, 0, 0, 0);
          }
        }
      } else if (wid < 5) {                // ksteps 16..39 : ctx part (uctx * 1/Z)
        float zi0 = 1.0f / Zb[dir*32 + b0];
        float zi1 = 1.0f / Zb[dir*32 + b1];
        const float* u0 = uctx + ((size_t)dir*32 + b0)*768;
        const float* u1 = uctx + ((size_t)dir*32 + b1)*768;
        #pragma unroll
        for (int kk = 0; kk < 8; kk++) {
          int kstep = wid*8 + kk;
          int ko = kstep*32 - 512 + lk8;
          float4 xa = *(const float4*)(u0 + ko);
          float4 xb4 = *(const float4*)(u0 + ko + 4);
          float4 ya = *(const float4*)(u1 + ko);
          float4 yb = *(const float4*)(u1 + ko + 4);
          short8v a0v, a1v;
          a0v[0]=(short)f2bf(xa.x*zi0);  a0v[1]=(short)f2bf(xa.y*zi0);
          a0v[2]=(short)f2bf(xa.z*zi0);  a0v[3]=(short)f2bf(xa.w*zi0);
          a0v[4]=(short)f2bf(xb4.x*zi0); a0v[5]=(short)f2bf(xb4.y*zi0);
          a0v[6]=(short)f2bf(xb4.z*zi0); a0v[7]=(short)f2bf(xb4.w*zi0);
          a1v[0]=(short)f2bf(ya.x*zi1);  a1v[1]=(short)f2bf(ya.y*zi1);
          a1v[2]=(short)f2bf(ya.z*zi1);  a1v[3]=(short)f2bf(ya.w*zi1);
          a1v[4]=(short)f2bf(yb.x*zi1);  a1v[5]=(short)f2bf(yb.y*zi1);
          a1v[6]=(short)f2bf(yb.z*zi1);  a1v[7]=(short)f2bf(yb.w*zi1);
          short8v bv = *(const short8v*)(wpb + (size_t)kstep*512 + lane*8);
          acc0 = __builtin_amdgcn_mfma_f32_16x16x32_bf16(a0v, bv, acc0, 0, 0, 0);
          acc1 = __builtin_amdgcn_mfma_f32_16x16x32_bf16(a1v, bv, acc1, 0, 0, 0);
        }
      } else {                             // ksteps 40..63 : x part
        const ushort* x0 = xb + ((size_t)b0*512 + t_in)*768;
        const ushort* x1 = xb + ((size_t)b1*512 + t_in)*768;
        #pragma unroll
        for (int kk = 0; kk < 8; kk++) {
          int kstep = wid*8 + kk;
          int ko = kstep*32 - 1280 + lk8;
          short8v a0v = *(const short8v*)(x0 + ko);
          short8v a1v = *(const short8v*)(x1 + ko);
          short8v bv  = *(const short8v*)(wpb + (size_t)kstep*512 + lane*8);
          acc0 = __builtin_amdgcn_mfma_f32_16x16x32_bf16(a0v, bv, acc0, 0, 0, 0);
          acc1 = __builtin_amdgcn_mfma_f32_16x16x32_bf16(a1v, bv, acc1, 0, 0, 0);
        }
      }

      int rr = (lane >> 4) * 4;
      #pragma unroll
      for (int r = 0; r < 4; r++) red[wid][rr + r][l15] = acc0[r];
      #pragma unroll
      for (int r = 0; r < 4; r++) red[wid][16 + rr + r][l15] = acc1[r];
      __syncthreads();
      {
        int b = tid >> 4, c = tid & 15;
        float g = 0.f;
        #pragma unroll
        for (int w = 0; w < 8; w++) g += red[w][b][c];
        gfin[b][c] = g;
      }
      __syncthreads();
      if (tid < 128) {
        int b = tid >> 2, jj = tid & 3;
        int j = jblk*4 + jj;
        const float* bias = dir ? bbv : bfv;
        float gi = gfin[b][jj]      + bias[j];
        float gf = gfin[b][4 + jj]  + bias[512 + j];
        float gg = gfin[b][8 + jj]  + bias[1024 + j];
        float go = gfin[b][12 + jj] + bias[1536 + j];
        size_t ci = ((size_t)dir*32 + b)*512 + j;
        float co = cst[ci];
        float cn = sigm_f(gf)*co + sigm_f(gi)*tanh_f(gg);
        float h  = sigm_f(go)*tanh_f(cn);
        cst[ci] = cn;
        int tw = dir ? (511 - s) : s;
        hsb[(((size_t)dir*512 + tw)*32 + b)*512 + j] = f2bf(h);
      }
    }
    grid.sync();
  }
}

// ---------------- head: out[b][t][c] = [hf|hb]·Whead^T + bhead
__global__ void k_head(const ushort* __restrict__ hsb, const float* __restrict__ Wh,
                       const float* __restrict__ bh, float* __restrict__ out)
{
  int wid = threadIdx.x >> 6, lane = threadIdx.x & 63;
  int r = blockIdx.x*4 + wid;
  int b = r >> 9, t = r & 511;
  float acc[7];
  #pragma unroll
  for (int c = 0; c < 7; c++) acc[c] = 0.f;
  const ushort* hf = hsb + (((size_t)t)*32 + b)*512;
  const ushort* hb = hsb + (((size_t)512 + t)*32 + b)*512;
  for (int k0 = 0; k0 < 512; k0 += 64) {
    int k = k0 + lane;
    float a = bf2f(hf[k]), bvv = bf2f(hb[k]);
    #pragma unroll
    for (int c = 0; c < 7; c++)
      acc[c] += a*Wh[c*1024 + k] + bvv*Wh[c*1024 + 512 + k];
  }
  #pragma unroll
  for (int c = 0; c < 7; c++) {
    float sres = acc[c];
    #pragma unroll
    for (int off = 32; off; off >>= 1) sres += __shfl_xor(sres, off);
    if (lane == c) out[((size_t)b*512 + t)*7 + c] = sres + bh[c];
  }
}

extern "C" void kernel_launch(void* const* d_in, const int* in_sizes, int n_in,
                              void* d_out, int out_size, void* d_ws, size_t ws_size,
                              hipStream_t stream) {
  (void)in_sizes; (void)n_in; (void)out_size;
  const float* x    = (const float*)d_in[0];
  const float* Wfih = (const float*)d_in[1];
  const float* Wfhh = (const float*)d_in[2];
  const float* bfv  = (const float*)d_in[3];
  const float* Wbih = (const float*)d_in[4];
  const float* Wbhh = (const float*)d_in[5];
  const float* bbv  = (const float*)d_in[6];
  const float* Wenc = (const float*)d_in[7];
  const float* benc = (const float*)d_in[8];
  const float* Wdec = (const float*)d_in[9];
  const float* bdec = (const float*)d_in[10];
  const float* v    = (const float*)d_in[11];
  const float* Whead= (const float*)d_in[12];
  const float* bhead= (const float*)d_in[13];
  float* out = (float*)d_out;
  char* ws = (char*)d_ws;

  if (ws_size < WS_BYTES) return;

  ushort* ep   = (ushort*)(ws + EPB);
  ushort* xb   = (ushort*)(ws + XBB);
  ushort* hsb  = (ushort*)(ws + HSB);
  ushort* wpk  = (ushort*)(ws + WPKB);
  ushort* wdp  = (ushort*)(ws + WDPB);
  float*  uctx = (float*)(ws + UCTXB);
  float*  Zb   = (float*)(ws + ZBB);
  float*  dec  = (float*)(ws + DECB);
  float*  cst  = (float*)(ws + CSTB);

  hipMemsetAsync(ws + CSTB, 0, (size_t)2*NB*HH*4, stream);

  hipLaunchKernelGGL(k_xcast, dim3(6144), dim3(256), 0, stream, x, xb);
  hipLaunchKernelGGL(k_encproj, dim3(8,8,32), dim3(256), 0, stream, x, Wenc, benc, ep);
  hipLaunchKernelGGL(k_wpack, dim3(4096), dim3(256), 0, stream, Wfih, Wfhh, Wbih, Wbhh, wpk);
  hipLaunchKernelGGL(k_wdpack, dim3(128), dim3(256), 0, stream, Wdec, wdp);

  void* args[] = {
    (void*)&hsb, (void*)&xb, (void*)&ep, (void*)&wpk, (void*)&wdp,
    (void*)&uctx, (void*)&Zb, (void*)&dec, (void*)&cst,
    (void*)&bdec, (void*)&v, (void*)&bfv, (void*)&bbv
  };
  hipLaunchCooperativeKernel(reinterpret_cast<void*>(k_loop), dim3(256), dim3(512),
                             args, 0, stream);

  hipLaunchKernelGGL(k_head, dim3(4096), dim3(256), 0, stream, hsb, Whead, bhead, out);
}

// Round 4
// 41015.820 us; speedup vs baseline: 1.5399x; 1.5399x over previous
//
#include <hip/hip_runtime.h>
#include <cstdint>
#include <cstddef>

#define L2E 1.4426950408889634f

typedef __attribute__((ext_vector_type(8))) short short8v;
typedef __attribute__((ext_vector_type(4))) float f32x4;

__device__ __forceinline__ float fexp2(float x){ return __builtin_amdgcn_exp2f(x); }
__device__ __forceinline__ float frcp(float x){ return __builtin_amdgcn_rcpf(x); }
__device__ __forceinline__ float tanh_f(float x){
  return 1.f - 2.f*frcp(1.f + fexp2(2.f*L2E*x));
}
__device__ __forceinline__ float sigm_f(float x){
  return frcp(1.f + fexp2(-L2E*x));
}
__device__ __forceinline__ float bf2f(ushort u){ return __uint_as_float(((uint32_t)u)<<16); }
__device__ __forceinline__ ushort f2bf(float f){
  uint32_t x = __float_as_uint(f);
  uint32_t r = (x + 0x7FFFu + ((x>>16)&1u)) >> 16;
  return (ushort)r;
}

// ---- custom grid barrier (agent scope: per-XCD L2 wb/inv only, L3 stays hot)
__device__ __forceinline__ void gbar(uint* cnt, uint target) {
  __syncthreads();                 // drains vmcnt for all waves of the block
  if (threadIdx.x == 0) {
    __hip_atomic_fetch_add(cnt, 1u, __ATOMIC_RELEASE, __HIP_MEMORY_SCOPE_AGENT);
    while (__hip_atomic_load(cnt, __ATOMIC_RELAXED, __HIP_MEMORY_SCOPE_AGENT) < target)
      __builtin_amdgcn_s_sleep(1);
    __builtin_amdgcn_fence(__ATOMIC_ACQUIRE, "agent");
  }
  __syncthreads();
}

namespace {
constexpr int NB = 32, TT = 512, DD = 768, HH = 512;
constexpr int NBLK = 256;
// byte offsets into ws
constexpr size_t EPB  = 0;                               // ep bf16 [B][H][T]
constexpr size_t XBB  = EPB  + (size_t)NB*HH*TT*2;       // x bf16 [B][T][D]
constexpr size_t HSB  = XBB  + (size_t)NB*TT*DD*2;       // hs bf16 [2][T][B][H]
constexpr size_t WPKB = HSB  + (size_t)2*TT*NB*HH*2;     // Wpack bf16 [2][128][64][64][8]
constexpr size_t WDPB = WPKB + (size_t)2*128*64*64*8*2;  // Wdec pack bf16 [32][16][64][8]
constexpr size_t UCTXB= WDPB + (size_t)32*16*64*8*2;     // uctx f32 [2][B][D]
constexpr size_t ZBB  = UCTXB+ (size_t)2*NB*DD*4;        // Z f32 [2][B]
constexpr size_t DECB = ZBB  + (size_t)2*NB*4;           // dec f32 [2][B][H]
constexpr size_t CSTB = DECB + (size_t)2*NB*HH*4;        // c f32 [2][B][H]
constexpr size_t GSYB = CSTB + (size_t)2*NB*HH*4;        // barrier counter
constexpr size_t WS_BYTES = GSYB + 256;
}

// ---------------- x -> bf16
__global__ void k_xcast(const float* __restrict__ x, ushort* __restrict__ xb)
{
  size_t i = ((size_t)blockIdx.x*256 + threadIdx.x)*8;
  float4 v0 = *(const float4*)(x + i);
  float4 v1 = *(const float4*)(x + i + 4);
  short8v o;
  o[0]=(short)f2bf(v0.x); o[1]=(short)f2bf(v0.y); o[2]=(short)f2bf(v0.z); o[3]=(short)f2bf(v0.w);
  o[4]=(short)f2bf(v1.x); o[5]=(short)f2bf(v1.y); o[6]=(short)f2bf(v1.z); o[7]=(short)f2bf(v1.w);
  *(short8v*)(xb + i) = o;
}

// ---------------- enc projection: ep[b][h][t] = x[b][t][:]·Wenc[h][:] + benc[h]
__global__ void k_encproj(const float* __restrict__ x, const float* __restrict__ Wenc,
                          const float* __restrict__ benc, ushort* __restrict__ epT)
{
  int b = blockIdx.z, h0 = blockIdx.y*64, t0 = blockIdx.x*64;
  __shared__ float As[64][33];
  __shared__ float Bs[64][33];
  int tid = threadIdx.x;
  int n = tid & 63, mg = tid >> 6;
  float acc[16];
  #pragma unroll
  for (int j = 0; j < 16; j++) acc[j] = 0.f;
  int lr = tid >> 2, lk = (tid & 3) * 8;
  for (int k0 = 0; k0 < 768; k0 += 32) {
    const float* ap = Wenc + (size_t)(h0 + lr)*768 + k0 + lk;
    #pragma unroll
    for (int i = 0; i < 8; i++) As[lr][lk + i] = ap[i];
    const float* bp = x + ((size_t)b*512 + t0 + lr)*768 + k0 + lk;
    #pragma unroll
    for (int i = 0; i < 8; i++) Bs[lr][lk + i] = bp[i];
    __syncthreads();
    #pragma unroll
    for (int kk = 0; kk < 32; kk++) {
      float bv = Bs[n][kk];
      #pragma unroll
      for (int j = 0; j < 16; j++) acc[j] += As[mg*16 + j][kk] * bv;
    }
    __syncthreads();
  }
  #pragma unroll
  for (int j = 0; j < 16; j++) {
    int h = h0 + mg*16 + j;
    epT[((size_t)b*512 + h)*512 + t0 + n] = f2bf(acc[j] + benc[h]);
  }
}

// ---------------- pre-pack gate weights into MFMA fragment order
__global__ void k_wpack(const float* __restrict__ Wfih, const float* __restrict__ Wfhh,
                        const float* __restrict__ Wbih, const float* __restrict__ Wbhh,
                        ushort* __restrict__ wpk)
{
  size_t f = (size_t)blockIdx.x*256 + threadIdx.x;   // 1,048,576 total
  int lane = (int)(f & 63), kstep = (int)((f>>6)&63), jblk = (int)((f>>12)&127), dir = (int)(f>>19);
  const float* Whh = dir ? Wbhh : Wfhh;
  const float* Wih = dir ? Wbih : Wfih;
  int c = lane & 15, gate = c >> 2, jj = c & 3;
  int row = gate*512 + jblk*4 + jj;
  int kbase = kstep*32 + (lane>>4)*8;
  short8v o;
  #pragma unroll
  for (int i = 0; i < 8; i++) {
    int k = kbase + i;
    float w = (k < 512) ? Whh[(size_t)row*512 + k] : Wih[(size_t)row*1536 + (k - 512)];
    o[i] = (short)f2bf(w);
  }
  *(short8v*)(wpk + f*8) = o;
}

// ---------------- pre-pack Wdec into MFMA B-fragment order [nb32][kstep16][lane64][8]
__global__ void k_wdpack(const float* __restrict__ Wdec, ushort* __restrict__ wdp)
{
  int f = blockIdx.x*256 + threadIdx.x;   // 32768 total
  int lane = f & 63, kstep = (f >> 6) & 15, nb = f >> 10;
  int n = nb*16 + (lane & 15);
  int kbase = kstep*32 + (lane >> 4)*8;
  short8v o;
  #pragma unroll
  for (int i = 0; i < 8; i++) o[i] = (short)f2bf(Wdec[(size_t)n*512 + kbase + i]);
  *(short8v*)(wdp + (size_t)f*8) = o;
}

// ---------------- persistent loop: 512 steps, 3 phases per step, custom barriers
__global__ __launch_bounds__(512, 2) void k_loop(
    ushort* __restrict__ hsb, const ushort* __restrict__ xb, const ushort* __restrict__ ep,
    const ushort* __restrict__ wpk, const ushort* __restrict__ wdp,
    float* __restrict__ uctx, float* __restrict__ Zb, float* __restrict__ dec,
    float* __restrict__ cst, const float* __restrict__ bdec, const float* __restrict__ vg,
    const float* __restrict__ bfv, const float* __restrict__ bbv, uint* __restrict__ gsync)
{
  __shared__ __align__(16) char smem[32768];
  const int bid = blockIdx.x;
  const int tid = threadIdx.x;
  const int wid = tid >> 6, lane = tid & 63;
  const int l15 = lane & 15, lk8 = (lane >> 4) * 8;
  uint bar_t = 0;

  for (int s = 0; s < TT; ++s) {
    // ======== phase D: dec = h_prev·Wdec^T + bdec (blocks 0..31, MFMA) ; zero uctx/Z (32..63)
    if (bid < 32) {
      int nb = bid;
      if (s == 0) {
        for (int e = tid; e < 1024; e += 512) {
          int row = e >> 4, col = e & 15;
          int m = row >> 4, rl = row & 15;
          int dir = m >> 1, b = (m & 1)*16 + rl;
          dec[((size_t)dir*32 + b)*512 + nb*16 + col] = bdec[nb*16 + col];
        }
      } else {
        float (*redD)[64][16] = (float(*)[64][16])smem;
        f32x4 acc[4] = {{0,0,0,0},{0,0,0,0},{0,0,0,0},{0,0,0,0}};
        int tp0 = s - 1, tp1 = 512 - s;
        #pragma unroll
        for (int kk = 0; kk < 2; kk++) {
          int kstep = wid*2 + kk;
          int ko = kstep*32 + lk8;
          short8v bv = *(const short8v*)(wdp + (((size_t)nb*16 + kstep)*64 + lane)*8);
          #pragma unroll
          for (int m = 0; m < 4; m++) {
            int dir = m >> 1, brow = (m & 1)*16 + l15;
            int tp = dir ? tp1 : tp0;
            const ushort* hp = hsb + (((size_t)dir*512 + tp)*32 + brow)*512 + ko;
            short8v av = *(const short8v*)hp;
            acc[m] = __builtin_amdgcn_mfma_f32_16x16x32_bf16(av, bv, acc[m], 0, 0, 0);
          }
        }
        #pragma unroll
        for (int m = 0; m < 4; m++)
          #pragma unroll
          for (int r = 0; r < 4; r++)
            redD[wid][m*16 + (lane>>4)*4 + r][l15] = acc[m][r];
        __syncthreads();
        for (int e = tid; e < 1024; e += 512) {
          int row = e >> 4, col = e & 15;
          float dv = 0.f;
          #pragma unroll
          for (int w = 0; w < 8; w++) dv += redD[w][row][col];
          int m = row >> 4, rl = row & 15;
          int dir = m >> 1, b = (m & 1)*16 + rl;
          dec[((size_t)dir*32 + b)*512 + nb*16 + col] = dv + bdec[nb*16 + col];
        }
      }
    } else if (bid < 64) {
      int base = (bid - 32)*512 + tid;
      for (int i = base; i < 2*32*768; i += 16384) uctx[i] = 0.f;
      if (base < 64) Zb[base] = 0.f;
    }
    bar_t += NBLK; gbar(gsync, bar_t);

    // ======== phase S: scores + shifted exp + unnormalized ctx (all 256 blocks)
    {
      float* sf = (float*)smem;
      float* d0 = sf; float* d1 = sf + 512; float* vsm = sf + 1024;
      float (*scr)[8][64] = (float(*)[8][64])(sf + 1536);
      float (*ev)[64] = (float(*)[64])(sf + 2560);
      int b = bid >> 3, tc = bid & 7, t0 = tc*64;
      d0[tid] = dec[(size_t)b*512 + tid];
      d1[tid] = dec[((size_t)32 + b)*512 + tid];
      vsm[tid] = vg[tid];
      __syncthreads();
      int tl = tid & 63, hg = tid >> 6;
      const ushort* epp = ep + ((size_t)b*512 + hg*64)*512 + t0 + tl;
      float s0 = 0.f, s1 = 0.f;
      #pragma unroll 8
      for (int hh = 0; hh < 64; hh++) {
        int h = hg*64 + hh;
        float e = bf2f(*epp); epp += 512;
        s0 += tanh_f(e + d0[h]) * vsm[h];
        s1 += tanh_f(e + d1[h]) * vsm[h];
      }
      scr[0][hg][tl] = s0; scr[1][hg][tl] = s1;
      __syncthreads();
      if (tid < 128) {
        int dq = tid >> 6, tq = tid & 63;
        float sv = 0.f;
        #pragma unroll
        for (int g = 0; g < 8; g++) sv += scr[dq][g][tq];
        sv = fminf(sv, 100.f);
        float e = fexp2((sv - 32.f)*L2E);
        ev[dq][tq] = e;
        float z = e;
        #pragma unroll
        for (int off = 32; off; off >>= 1) z += __shfl_xor(z, off);
        if (tq == 0) atomicAdd(Zb + dq*32 + b, z);
      }
      __syncthreads();
      for (int dd = tid; dd < 768; dd += 512) {
        const ushort* xp = xb + ((size_t)b*512 + t0)*768 + dd;
        float a0 = 0.f, a1 = 0.f;
        #pragma unroll 8
        for (int t = 0; t < 64; t++) {
          float xv = bf2f(xp[(size_t)t*768]);
          a0 += ev[0][t]*xv;
          a1 += ev[1][t]*xv;
        }
        atomicAdd(uctx + (size_t)b*768 + dd, a0);
        atomicAdd(uctx + ((size_t)32 + b)*768 + dd, a1);
      }
    }
    bar_t += NBLK; gbar(gsync, bar_t);

    // ======== phase G: gates MFMA GEMM (K=2048 = h|ctx|x) + fused LSTM pointwise
    {
      float (*red)[32][16] = (float(*)[32][16])smem;
      float (*gfin)[17] = (float(*)[17])(smem + 16384);
      int dir = bid >> 7, jblk = bid & 127;
      int t_in = dir ? (511 - s) : s;
      int b0 = l15, b1 = 16 + l15;
      f32x4 acc0 = {0,0,0,0}, acc1 = {0,0,0,0};
      const ushort* wpb = wpk + (((size_t)dir*128 + jblk)*64)*512;

      if (wid < 2) {                       // ksteps 0..15 : h_prev part
        if (s > 0) {
          int t_prev = dir ? (512 - s) : (s - 1);
          const ushort* h0 = hsb + (((size_t)dir*512 + t_prev)*32 + b0)*512;
          const ushort* h1 = hsb + (((size_t)dir*512 + t_prev)*32 + b1)*512;
          #pragma unroll
          for (int kk = 0; kk < 8; kk++) {
            int kstep = wid*8 + kk;
            int ko = kstep*32 + lk8;
            short8v a0v = *(const short8v*)(h0 + ko);
            short8v a1v = *(const short8v*)(h1 + ko);
            short8v bv  = *(const short8v*)(wpb + (size_t)kstep*512 + lane*8);
            acc0 = __builtin_amdgcn_mfma_f32_16x16x32_bf16(a0v, bv, acc0, 0, 0, 0);
            acc1 = __builtin_amdgcn_mfma_f32_16x16x32_bf16(a1v, bv, acc1, 0, 0, 0);
          }
        }
      } else if (wid < 5) {                // ksteps 16..39 : ctx part (uctx * 1/Z)
        float zi0 = 1.0f / Zb[dir*32 + b0];
        float zi1 = 1.0f / Zb[dir*32 + b1];
        const float* u0 = uctx + ((size_t)dir*32 + b0)*768;
        const float* u1 = uctx + ((size_t)dir*32 + b1)*768;
        #pragma unroll
        for (int kk = 0; kk < 8; kk++) {
          int kstep = wid*8 + kk;
          int ko = kstep*32 - 512 + lk8;
          float4 xa = *(const float4*)(u0 + ko);
          float4 xb4 = *(const float4*)(u0 + ko + 4);
          float4 ya = *(const float4*)(u1 + ko);
          float4 yb = *(const float4*)(u1 + ko + 4);
          short8v a0v, a1v;
          a0v[0]=(short)f2bf(xa.x*zi0);  a0v[1]=(short)f2bf(xa.y*zi0);
          a0v[2]=(short)f2bf(xa.z*zi0);  a0v[3]=(short)f2bf(xa.w*zi0);
          a0v[4]=(short)f2bf(xb4.x*zi0); a0v[5]=(short)f2bf(xb4.y*zi0);
          a0v[6]=(short)f2bf(xb4.z*zi0); a0v[7]=(short)f2bf(xb4.w*zi0);
          a1v[0]=(short)f2bf(ya.x*zi1);  a1v[1]=(short)f2bf(ya.y*zi1);
          a1v[2]=(short)f2bf(ya.z*zi1);  a1v[3]=(short)f2bf(ya.w*zi1);
          a1v[4]=(short)f2bf(yb.x*zi1);  a1v[5]=(short)f2bf(yb.y*zi1);
          a1v[6]=(short)f2bf(yb.z*zi1);  a1v[7]=(short)f2bf(yb.w*zi1);
          short8v bv = *(const short8v*)(wpb + (size_t)kstep*512 + lane*8);
          acc0 = __builtin_amdgcn_mfma_f32_16x16x32_bf16(a0v, bv, acc0, 0, 0, 0);
          acc1 = __builtin_amdgcn_mfma_f32_16x16x32_bf16(a1v, bv, acc1, 0, 0, 0);
        }
      } else {                             // ksteps 40..63 : x part
        const ushort* x0 = xb + ((size_t)b0*512 + t_in)*768;
        const ushort* x1 = xb + ((size_t)b1*512 + t_in)*768;
        #pragma unroll
        for (int kk = 0; kk < 8; kk++) {
          int kstep = wid*8 + kk;
          int ko = kstep*32 - 1280 + lk8;
          short8v a0v = *(const short8v*)(x0 + ko);
          short8v a1v = *(const short8v*)(x1 + ko);
          short8v bv  = *(const short8v*)(wpb + (size_t)kstep*512 + lane*8);
          acc0 = __builtin_amdgcn_mfma_f32_16x16x32_bf16(a0v, bv, acc0, 0, 0, 0);
          acc1 = __builtin_amdgcn_mfma_f32_16x16x32_bf16(a1v, bv, acc1, 0, 0, 0);
        }
      }

      int rr = (lane >> 4) * 4;
      #pragma unroll
      for (int r = 0; r < 4; r++) red[wid][rr + r][l15] = acc0[r];
      #pragma unroll
      for (int r = 0; r < 4; r++) red[wid][16 + rr + r][l15] = acc1[r];
      __syncthreads();
      {
        int b = tid >> 4, c = tid & 15;
        float g = 0.f;
        #pragma unroll
        for (int w = 0; w < 8; w++) g += red[w][b][c];
        gfin[b][c] = g;
      }
      __syncthreads();
      if (tid < 128) {
        int b = tid >> 2, jj = tid & 3;
        int j = jblk*4 + jj;
        const float* bias = dir ? bbv : bfv;
        float gi = gfin[b][jj]      + bias[j];
        float gf = gfin[b][4 + jj]  + bias[512 + j];
        float gg = gfin[b][8 + jj]  + bias[1024 + j];
        float go = gfin[b][12 + jj] + bias[1536 + j];
        size_t ci = ((size_t)dir*32 + b)*512 + j;
        float co = cst[ci];
        float cn = sigm_f(gf)*co + sigm_f(gi)*tanh_f(gg);
        float h  = sigm_f(go)*tanh_f(cn);
        cst[ci] = cn;
        int tw = dir ? (511 - s) : s;
        hsb[(((size_t)dir*512 + tw)*32 + b)*512 + j] = f2bf(h);
      }
    }
    bar_t += NBLK; gbar(gsync, bar_t);
  }
}

// ---------------- head: out[b][t][c] = [hf|hb]·Whead^T + bhead
__global__ void k_head(const ushort* __restrict__ hsb, const float* __restrict__ Wh,
                       const float* __restrict__ bh, float* __restrict__ out)
{
  int wid = threadIdx.x >> 6, lane = threadIdx.x & 63;
  int r = blockIdx.x*4 + wid;
  int b = r >> 9, t = r & 511;
  float acc[7];
  #pragma unroll
  for (int c = 0; c < 7; c++) acc[c] = 0.f;
  const ushort* hf = hsb + (((size_t)t)*32 + b)*512;
  const ushort* hb = hsb + (((size_t)512 + t)*32 + b)*512;
  for (int k0 = 0; k0 < 512; k0 += 64) {
    int k = k0 + lane;
    float a = bf2f(hf[k]), bvv = bf2f(hb[k]);
    #pragma unroll
    for (int c = 0; c < 7; c++)
      acc[c] += a*Wh[c*1024 + k] + bvv*Wh[c*1024 + 512 + k];
  }
  #pragma unroll
  for (int c = 0; c < 7; c++) {
    float sres = acc[c];
    #pragma unroll
    for (int off = 32; off; off >>= 1) sres += __shfl_xor(sres, off);
    if (lane == c) out[((size_t)b*512 + t)*7 + c] = sres + bh[c];
  }
}

extern "C" void kernel_launch(void* const* d_in, const int* in_sizes, int n_in,
                              void* d_out, int out_size, void* d_ws, size_t ws_size,
                              hipStream_t stream) {
  (void)in_sizes; (void)n_in; (void)out_size;
  const float* x    = (const float*)d_in[0];
  const float* Wfih = (const float*)d_in[1];
  const float* Wfhh = (const float*)d_in[2];
  const float* bfv  = (const float*)d_in[3];
  const float* Wbih = (const float*)d_in[4];
  const float* Wbhh = (const float*)d_in[5];
  const float* bbv  = (const float*)d_in[6];
  const float* Wenc = (const float*)d_in[7];
  const float* benc = (const float*)d_in[8];
  const float* Wdec = (const float*)d_in[9];
  const float* bdec = (const float*)d_in[10];
  const float* v    = (const float*)d_in[11];
  const float* Whead= (const float*)d_in[12];
  const float* bhead= (const float*)d_in[13];
  float* out = (float*)d_out;
  char* ws = (char*)d_ws;

  if (ws_size < WS_BYTES) return;

  ushort* ep   = (ushort*)(ws + EPB);
  ushort* xb   = (ushort*)(ws + XBB);
  ushort* hsb  = (ushort*)(ws + HSB);
  ushort* wpk  = (ushort*)(ws + WPKB);
  ushort* wdp  = (ushort*)(ws + WDPB);
  float*  uctx = (float*)(ws + UCTXB);
  float*  Zb   = (float*)(ws + ZBB);
  float*  dec  = (float*)(ws + DECB);
  float*  cst  = (float*)(ws + CSTB);
  uint*   gsync= (uint*)(ws + GSYB);

  hipMemsetAsync(ws + CSTB, 0, (size_t)2*NB*HH*4, stream);
  hipMemsetAsync(ws + GSYB, 0, 256, stream);

  hipLaunchKernelGGL(k_xcast, dim3(6144), dim3(256), 0, stream, x, xb);
  hipLaunchKernelGGL(k_encproj, dim3(8,8,32), dim3(256), 0, stream, x, Wenc, benc, ep);
  hipLaunchKernelGGL(k_wpack, dim3(4096), dim3(256), 0, stream, Wfih, Wfhh, Wbih, Wbhh, wpk);
  hipLaunchKernelGGL(k_wdpack, dim3(128), dim3(256), 0, stream, Wdec, wdp);

  void* args[] = {
    (void*)&hsb, (void*)&xb, (void*)&ep, (void*)&wpk, (void*)&wdp,
    (void*)&uctx, (void*)&Zb, (void*)&dec, (void*)&cst,
    (void*)&bdec, (void*)&v, (void*)&bfv, (void*)&bbv, (void*)&gsync
  };
  hipLaunchCooperativeKernel(reinterpret_cast<void*>(k_loop), dim3(256), dim3(512),
                             args, 0, stream);

  hipLaunchKernelGGL(k_head, dim3(4096), dim3(256), 0, stream, hsb, Whead, bhead, out);
}

// Round 5
// 17737.927 us; speedup vs baseline: 3.5606x; 2.3123x over previous
//
#include <hip/hip_runtime.h>
#include <cstdint>
#include <cstddef>

#define L2E 1.4426950408889634f

typedef __attribute__((ext_vector_type(8))) short short8v;
typedef __attribute__((ext_vector_type(4))) float f32x4;
typedef unsigned long long ull;

__device__ __forceinline__ float fexp2(float x){ return __builtin_amdgcn_exp2f(x); }
__device__ __forceinline__ float frcp(float x){ return __builtin_amdgcn_rcpf(x); }
__device__ __forceinline__ float tanh_f(float x){
  return 1.f - 2.f*frcp(1.f + fexp2(2.f*L2E*x));
}
__device__ __forceinline__ float sigm_f(float x){
  return frcp(1.f + fexp2(-L2E*x));
}
__device__ __forceinline__ float bf2f(ushort u){ return __uint_as_float(((uint32_t)u)<<16); }
__device__ __forceinline__ ushort f2bf(float f){
  uint32_t x = __float_as_uint(f);
  uint32_t r = (x + 0x7FFFu + ((x>>16)&1u)) >> 16;
  return (ushort)r;
}

// ---- coherent (agent-scope, L2-bypassing) access helpers: no cache fences needed
__device__ __forceinline__ float ld4f(const float* p){
  return __hip_atomic_load((float*)p, __ATOMIC_RELAXED, __HIP_MEMORY_SCOPE_AGENT);
}
__device__ __forceinline__ void st4f(float* p, float v){
  __hip_atomic_store(p, v, __ATOMIC_RELAXED, __HIP_MEMORY_SCOPE_AGENT);
}
__device__ __forceinline__ float2 ld8f(const float* p){
  union { ull u; float2 f; } c;
  c.u = __hip_atomic_load((ull*)p, __ATOMIC_RELAXED, __HIP_MEMORY_SCOPE_AGENT);
  return c.f;
}
__device__ __forceinline__ short8v ld16h(const ushort* p){
  union { ull u[2]; short8v s; } c;
  c.u[0] = __hip_atomic_load((ull*)p,     __ATOMIC_RELAXED, __HIP_MEMORY_SCOPE_AGENT);
  c.u[1] = __hip_atomic_load((ull*)(p+4), __ATOMIC_RELAXED, __HIP_MEMORY_SCOPE_AGENT);
  return c.s;
}
__device__ __forceinline__ void st8u(ushort* p, ull v){
  __hip_atomic_store((ull*)p, v, __ATOMIC_RELAXED, __HIP_MEMORY_SCOPE_AGENT);
}

namespace {
constexpr int NB = 32, TT = 512, DD = 768, HH = 512;
// byte offsets into ws
constexpr size_t EPB  = 0;                               // ep bf16 [B][H][T]
constexpr size_t XBB  = EPB  + (size_t)NB*HH*TT*2;       // x bf16 [B][T][D]
constexpr size_t HSB  = XBB  + (size_t)NB*TT*DD*2;       // hs bf16 [2][T][B][H]
constexpr size_t WPKB = HSB  + (size_t)2*TT*NB*HH*2;     // Wpack bf16 [2][128][64][64][8]
constexpr size_t WDPB = WPKB + (size_t)2*128*64*64*8*2;  // Wdec pack bf16 [32][16][64][8]
constexpr size_t UCTXB= WDPB + (size_t)32*16*64*8*2;     // uctx f32 [2][B][D]
constexpr size_t ZBB  = UCTXB+ (size_t)2*NB*DD*4;        // Z f32 [2][B]
constexpr size_t DECB = ZBB  + (size_t)2*NB*4;           // dec f32 [2][B][H]
constexpr size_t CSTB = DECB + (size_t)2*NB*HH*4;        // c f32 [2][B][H]
constexpr size_t GSYB = CSTB + (size_t)2*NB*HH*4;        // barrier flags (256*64B) + go
constexpr size_t WS_BYTES = GSYB + 32768;

// dynamic LDS layout (bytes)
constexpr int EPL = 0;            // ushort[512][64]  ep slice (S role)
constexpr int WPL = 65536;        // ushort[64][512]  wpk slice (G role)
constexpr int SCR = 131072;       // scratch union (S: 10.75 KB, G/D: 18.2 KB)
constexpr int LDS_BYTES = 149632;
}

// ---- flag-array grid barrier: release by waitcnt+flag store; NO cache invalidation
__device__ __forceinline__ void gbar2(uint* flags, uint* go, uint token, int bid, int tid){
  __syncthreads();
  asm volatile("s_waitcnt vmcnt(0)" ::: "memory");
  if (bid == 0) {
    if (tid < 256) {
      if (tid == 0)
        __hip_atomic_store(&flags[0], token, __ATOMIC_RELAXED, __HIP_MEMORY_SCOPE_AGENT);
      while (__hip_atomic_load(&flags[tid*16], __ATOMIC_RELAXED, __HIP_MEMORY_SCOPE_AGENT) < token)
        __builtin_amdgcn_s_sleep(1);
    }
    __syncthreads();
    if (tid == 0)
      __hip_atomic_store(go, token, __ATOMIC_RELAXED, __HIP_MEMORY_SCOPE_AGENT);
  } else {
    if (tid == 0) {
      __hip_atomic_store(&flags[bid*16], token, __ATOMIC_RELAXED, __HIP_MEMORY_SCOPE_AGENT);
      while (__hip_atomic_load(go, __ATOMIC_RELAXED, __HIP_MEMORY_SCOPE_AGENT) < token)
        __builtin_amdgcn_s_sleep(1);
    }
    __syncthreads();
  }
  asm volatile("" ::: "memory");
}

// ---------------- x -> bf16
__global__ void k_xcast(const float* __restrict__ x, ushort* __restrict__ xb)
{
  size_t i = ((size_t)blockIdx.x*256 + threadIdx.x)*8;
  float4 v0 = *(const float4*)(x + i);
  float4 v1 = *(const float4*)(x + i + 4);
  short8v o;
  o[0]=(short)f2bf(v0.x); o[1]=(short)f2bf(v0.y); o[2]=(short)f2bf(v0.z); o[3]=(short)f2bf(v0.w);
  o[4]=(short)f2bf(v1.x); o[5]=(short)f2bf(v1.y); o[6]=(short)f2bf(v1.z); o[7]=(short)f2bf(v1.w);
  *(short8v*)(xb + i) = o;
}

// ---------------- enc projection: ep[b][h][t] = x[b][t][:]·Wenc[h][:] + benc[h]
__global__ void k_encproj(const float* __restrict__ x, const float* __restrict__ Wenc,
                          const float* __restrict__ benc, ushort* __restrict__ epT)
{
  int b = blockIdx.z, h0 = blockIdx.y*64, t0 = blockIdx.x*64;
  __shared__ float As[64][33];
  __shared__ float Bs[64][33];
  int tid = threadIdx.x;
  int n = tid & 63, mg = tid >> 6;
  float acc[16];
  #pragma unroll
  for (int j = 0; j < 16; j++) acc[j] = 0.f;
  int lr = tid >> 2, lk = (tid & 3) * 8;
  for (int k0 = 0; k0 < 768; k0 += 32) {
    const float* ap = Wenc + (size_t)(h0 + lr)*768 + k0 + lk;
    #pragma unroll
    for (int i = 0; i < 8; i++) As[lr][lk + i] = ap[i];
    const float* bp = x + ((size_t)b*512 + t0 + lr)*768 + k0 + lk;
    #pragma unroll
    for (int i = 0; i < 8; i++) Bs[lr][lk + i] = bp[i];
    __syncthreads();
    #pragma unroll
    for (int kk = 0; kk < 32; kk++) {
      float bv = Bs[n][kk];
      #pragma unroll
      for (int j = 0; j < 16; j++) acc[j] += As[mg*16 + j][kk] * bv;
    }
    __syncthreads();
  }
  #pragma unroll
  for (int j = 0; j < 16; j++) {
    int h = h0 + mg*16 + j;
    epT[((size_t)b*512 + h)*512 + t0 + n] = f2bf(acc[j] + benc[h]);
  }
}

// ---------------- pre-pack gate weights into MFMA fragment order
__global__ void k_wpack(const float* __restrict__ Wfih, const float* __restrict__ Wfhh,
                        const float* __restrict__ Wbih, const float* __restrict__ Wbhh,
                        ushort* __restrict__ wpk)
{
  size_t f = (size_t)blockIdx.x*256 + threadIdx.x;   // 1,048,576 total
  int lane = (int)(f & 63), kstep = (int)((f>>6)&63), jblk = (int)((f>>12)&127), dir = (int)(f>>19);
  const float* Whh = dir ? Wbhh : Wfhh;
  const float* Wih = dir ? Wbih : Wfih;
  int c = lane & 15, gate = c >> 2, jj = c & 3;
  int row = gate*512 + jblk*4 + jj;
  int kbase = kstep*32 + (lane>>4)*8;
  short8v o;
  #pragma unroll
  for (int i = 0; i < 8; i++) {
    int k = kbase + i;
    float w = (k < 512) ? Whh[(size_t)row*512 + k] : Wih[(size_t)row*1536 + (k - 512)];
    o[i] = (short)f2bf(w);
  }
  *(short8v*)(wpk + f*8) = o;
}

// ---------------- pre-pack Wdec into MFMA B-fragment order [nb32][kstep16][lane64][8]
__global__ void k_wdpack(const float* __restrict__ Wdec, ushort* __restrict__ wdp)
{
  int f = blockIdx.x*256 + threadIdx.x;   // 32768 total
  int lane = f & 63, kstep = (f >> 6) & 15, nb = f >> 10;
  int n = nb*16 + (lane & 15);
  int kbase = kstep*32 + (lane >> 4)*8;
  short8v o;
  #pragma unroll
  for (int i = 0; i < 8; i++) o[i] = (short)f2bf(Wdec[(size_t)n*512 + kbase + i]);
  *(short8v*)(wdp + (size_t)f*8) = o;
}

// ---------------- persistent loop: 512 steps, 3 phases, flag barriers, LDS-pinned ep/wpk
__global__ __launch_bounds__(512, 1) void k_loop(
    ushort* __restrict__ hsb, const ushort* __restrict__ xb, const ushort* __restrict__ ep,
    const ushort* __restrict__ wpk, const ushort* __restrict__ wdp,
    float* __restrict__ uctx, float* __restrict__ Zb, float* __restrict__ dec,
    float* __restrict__ cst, const float* __restrict__ bdec, const float* __restrict__ vg,
    const float* __restrict__ bfv, const float* __restrict__ bbv,
    uint* __restrict__ flags, uint* __restrict__ go)
{
  extern __shared__ __align__(16) char dsm[];
  ushort* ep_l  = (ushort*)(dsm + EPL);   // [512 h][64 t]
  ushort* wpk_l = (ushort*)(dsm + WPL);   // [64 kstep][512]
  float*  RED   = (float*)(dsm + SCR);    // [8][32][16] (G/D)
  float*  GFIN  = (float*)(dsm + SCR + 16384); // [32][17]  (G)
  float*  DEC2  = (float*)(dsm + SCR);          // [2][512]  (S)
  float*  VSM   = (float*)(dsm + SCR + 4096);   // [512]     (S)
  float*  SCRS  = (float*)(dsm + SCR + 6144);   // [2][8][64](S)
  float*  EVS   = (float*)(dsm + SCR + 10240);  // [2][64]   (S)

  const int bid = blockIdx.x;
  const int tid = threadIdx.x;
  const int wid = tid >> 6, lane = tid & 63;
  const int l15 = lane & 15, lk8 = (lane >> 4) * 8;
  const int bS = bid >> 3, t0 = (bid & 7) * 64;        // S role
  const int dirG = bid >> 7, jblkG = bid & 127;        // G role
  uint bar_t = 0;

  // ---- one-time preload of pinned LDS slices
  {
    const ushort* esrc = ep + ((size_t)bS*512)*512 + t0;
    for (int i = tid; i < 4096; i += 512) {
      int h = i >> 3, c = i & 7;
      *(short8v*)(ep_l + h*64 + c*8) = *(const short8v*)(esrc + (size_t)h*512 + c*8);
    }
    const ushort* wsrc = wpk + (((size_t)dirG*128 + jblkG)*64)*512;
    for (int i = tid; i < 4096; i += 512)
      ((short8v*)wpk_l)[i] = ((const short8v*)wsrc)[i];
  }
  __syncthreads();

  for (int s = 0; s < TT; ++s) {
    // ======== phase D: dec = h_prev·Wdec^T + bdec (blocks 0..31); zero uctx/Z (32..63)
    if (bid < 32) {
      int nb = bid;
      if (s == 0) {
        for (int e = tid; e < 1024; e += 512) {
          int row = e >> 4, col = e & 15;                 // row = dir*32+b
          st4f(dec + (size_t)row*512 + nb*16 + col, bdec[nb*16 + col]);
        }
      } else {
        f32x4 acc[4] = {{0,0,0,0},{0,0,0,0},{0,0,0,0},{0,0,0,0}};
        int tp0 = s - 1, tp1 = 512 - s;
        #pragma unroll
        for (int kk = 0; kk < 2; kk++) {
          int kstep = wid*2 + kk;
          int ko = kstep*32 + lk8;
          short8v bv = *(const short8v*)(wdp + (((size_t)nb*16 + kstep)*64 + lane)*8);
          #pragma unroll
          for (int m = 0; m < 4; m++) {
            int dir = m >> 1, brow = (m & 1)*16 + l15;
            int tp = dir ? tp1 : tp0;
            short8v av = ld16h(hsb + (((size_t)dir*512 + tp)*32 + brow)*512 + ko);
            acc[m] = __builtin_amdgcn_mfma_f32_16x16x32_bf16(av, bv, acc[m], 0, 0, 0);
          }
        }
        int rr = (lane >> 4) * 4;
        #pragma unroll
        for (int pass = 0; pass < 2; pass++) {            // pass0: dir0 (m0,1), pass1: dir1 (m2,3)
          #pragma unroll
          for (int mh = 0; mh < 2; mh++)
            #pragma unroll
            for (int r = 0; r < 4; r++)
              RED[((size_t)wid*32 + mh*16 + rr + r)*16 + l15] = acc[pass*2 + mh][r];
          __syncthreads();
          if (tid < 512) {
            int row = tid >> 4, col = tid & 15;           // row = b (0..31)
            float dv = 0.f;
            #pragma unroll
            for (int w = 0; w < 8; w++) dv += RED[((size_t)w*32 + row)*16 + col];
            st4f(dec + ((size_t)pass*32 + row)*512 + nb*16 + col, dv + bdec[nb*16 + col]);
          }
          __syncthreads();
        }
      }
    } else if (bid < 64) {
      int base = (bid - 32)*512 + tid;
      for (int i = base; i < 2*32*768; i += 16384) st4f(uctx + i, 0.f);
      if (base < 64) st4f(Zb + base, 0.f);
    }
    gbar2(flags, go, ++bar_t, bid, tid);

    // ======== phase S: scores (ep from LDS) + shifted exp + unnormalized ctx atomics
    {
      DEC2[tid]       = ld4f(dec + (size_t)bS*512 + tid);
      DEC2[512 + tid] = ld4f(dec + ((size_t)32 + bS)*512 + tid);
      VSM[tid] = vg[tid];
      __syncthreads();
      int tl = tid & 63, hg = tid >> 6;
      float s0 = 0.f, s1 = 0.f;
      #pragma unroll 8
      for (int hh = 0; hh < 64; hh++) {
        int h = hg*64 + hh;
        float e = bf2f(ep_l[(size_t)h*64 + tl]);
        float vv = VSM[h];
        s0 += tanh_f(e + DEC2[h]) * vv;
        s1 += tanh_f(e + DEC2[512 + h]) * vv;
      }
      SCRS[((size_t)0*8 + hg)*64 + tl] = s0;
      SCRS[((size_t)1*8 + hg)*64 + tl] = s1;
      __syncthreads();
      if (tid < 128) {
        int dq = tid >> 6, tq = tid & 63;
        float sv = 0.f;
        #pragma unroll
        for (int g = 0; g < 8; g++) sv += SCRS[((size_t)dq*8 + g)*64 + tq];
        sv = fminf(sv, 100.f);
        float e = fexp2((sv - 32.f)*L2E);
        EVS[dq*64 + tq] = e;
        float z = e;
        #pragma unroll
        for (int off = 32; off; off >>= 1) z += __shfl_xor(z, off);
        if (tq == 0) unsafeAtomicAdd(Zb + dq*32 + bS, z);
      }
      __syncthreads();
      for (int dd = tid; dd < 768; dd += 512) {
        const ushort* xp = xb + ((size_t)bS*512 + t0)*768 + dd;
        float a0 = 0.f, a1 = 0.f;
        #pragma unroll 8
        for (int t = 0; t < 64; t++) {
          float xv = bf2f(xp[(size_t)t*768]);
          a0 += EVS[t]*xv;
          a1 += EVS[64 + t]*xv;
        }
        unsafeAtomicAdd(uctx + (size_t)bS*768 + dd, a0);
        unsafeAtomicAdd(uctx + ((size_t)32 + bS)*768 + dd, a1);
      }
    }
    gbar2(flags, go, ++bar_t, bid, tid);

    // ======== phase G: gates MFMA GEMM (K=2048 = h|ctx|x, B from LDS) + fused LSTM
    {
      int dir = dirG, jblk = jblkG;
      int t_in = dir ? (511 - s) : s;
      int b0 = l15, b1 = 16 + l15;
      f32x4 acc0 = {0,0,0,0}, acc1 = {0,0,0,0};

      if (wid < 2) {                       // ksteps 0..15 : h_prev part
        if (s > 0) {
          int t_prev = dir ? (512 - s) : (s - 1);
          const ushort* h0 = hsb + (((size_t)dir*512 + t_prev)*32 + b0)*512;
          const ushort* h1 = hsb + (((size_t)dir*512 + t_prev)*32 + b1)*512;
          #pragma unroll
          for (int kk = 0; kk < 8; kk++) {
            int kstep = wid*8 + kk;
            int ko = kstep*32 + lk8;
            short8v a0v = ld16h(h0 + ko);
            short8v a1v = ld16h(h1 + ko);
            short8v bv  = *(const short8v*)(wpk_l + (size_t)kstep*512 + lane*8);
            acc0 = __builtin_amdgcn_mfma_f32_16x16x32_bf16(a0v, bv, acc0, 0, 0, 0);
            acc1 = __builtin_amdgcn_mfma_f32_16x16x32_bf16(a1v, bv, acc1, 0, 0, 0);
          }
        }
      } else if (wid < 5) {                // ksteps 16..39 : ctx part (uctx * 1/Z)
        float zi0 = 1.0f / ld4f(Zb + dir*32 + b0);
        float zi1 = 1.0f / ld4f(Zb + dir*32 + b1);
        const float* u0 = uctx + ((size_t)dir*32 + b0)*768;
        const float* u1 = uctx + ((size_t)dir*32 + b1)*768;
        #pragma unroll
        for (int kk = 0; kk < 8; kk++) {
          int kstep = wid*8 + kk;
          int ko = kstep*32 - 512 + lk8;
          float2 xa = ld8f(u0 + ko),     xc = ld8f(u0 + ko + 2);
          float2 xe = ld8f(u0 + ko + 4), xg = ld8f(u0 + ko + 6);
          float2 ya = ld8f(u1 + ko),     yc = ld8f(u1 + ko + 2);
          float2 ye = ld8f(u1 + ko + 4), yg = ld8f(u1 + ko + 6);
          short8v a0v, a1v;
          a0v[0]=(short)f2bf(xa.x*zi0); a0v[1]=(short)f2bf(xa.y*zi0);
          a0v[2]=(short)f2bf(xc.x*zi0); a0v[3]=(short)f2bf(xc.y*zi0);
          a0v[4]=(short)f2bf(xe.x*zi0); a0v[5]=(short)f2bf(xe.y*zi0);
          a0v[6]=(short)f2bf(xg.x*zi0); a0v[7]=(short)f2bf(xg.y*zi0);
          a1v[0]=(short)f2bf(ya.x*zi1); a1v[1]=(short)f2bf(ya.y*zi1);
          a1v[2]=(short)f2bf(yc.x*zi1); a1v[3]=(short)f2bf(yc.y*zi1);
          a1v[4]=(short)f2bf(ye.x*zi1); a1v[5]=(short)f2bf(ye.y*zi1);
          a1v[6]=(short)f2bf(yg.x*zi1); a1v[7]=(short)f2bf(yg.y*zi1);
          short8v bv = *(const short8v*)(wpk_l + (size_t)kstep*512 + lane*8);
          acc0 = __builtin_amdgcn_mfma_f32_16x16x32_bf16(a0v, bv, acc0, 0, 0, 0);
          acc1 = __builtin_amdgcn_mfma_f32_16x16x32_bf16(a1v, bv, acc1, 0, 0, 0);
        }
      } else {                             // ksteps 40..63 : x part (nontemporal)
        const ushort* x0 = xb + ((size_t)b0*512 + t_in)*768;
        const ushort* x1 = xb + ((size_t)b1*512 + t_in)*768;
        #pragma unroll
        for (int kk = 0; kk < 8; kk++) {
          int kstep = wid*8 + kk;
          int ko = kstep*32 - 1280 + lk8;
          short8v a0v = __builtin_nontemporal_load((const short8v*)(x0 + ko));
          short8v a1v = __builtin_nontemporal_load((const short8v*)(x1 + ko));
          short8v bv  = *(const short8v*)(wpk_l + (size_t)kstep*512 + lane*8);
          acc0 = __builtin_amdgcn_mfma_f32_16x16x32_bf16(a0v, bv, acc0, 0, 0, 0);
          acc1 = __builtin_amdgcn_mfma_f32_16x16x32_bf16(a1v, bv, acc1, 0, 0, 0);
        }
      }

      int rr = (lane >> 4) * 4;
      #pragma unroll
      for (int r = 0; r < 4; r++) RED[((size_t)wid*32 + rr + r)*16 + l15] = acc0[r];
      #pragma unroll
      for (int r = 0; r < 4; r++) RED[((size_t)wid*32 + 16 + rr + r)*16 + l15] = acc1[r];
      __syncthreads();
      {
        int b = tid >> 4, c = tid & 15;
        float g = 0.f;
        #pragma unroll
        for (int w = 0; w < 8; w++) g += RED[((size_t)w*32 + b)*16 + c];
        GFIN[b*17 + c] = g;
      }
      __syncthreads();
      if (tid < 32) {
        int b = tid;
        int j0 = jblk*4;
        const float* bias = dir ? bbv : bfv;
        size_t ci0 = ((size_t)dir*32 + b)*512 + j0;
        float4 co = *(const float4*)&cst[ci0];
        float cold[4] = {co.x, co.y, co.z, co.w};
        float4 cn4;
        ull hp = 0;
        #pragma unroll
        for (int jj = 0; jj < 4; jj++) {
          int j = j0 + jj;
          float gi = GFIN[b*17 + jj]      + bias[j];
          float gf = GFIN[b*17 + 4 + jj]  + bias[512 + j];
          float gg = GFIN[b*17 + 8 + jj]  + bias[1024 + j];
          float go_ = GFIN[b*17 + 12 + jj]+ bias[1536 + j];
          float cn = sigm_f(gf)*cold[jj] + sigm_f(gi)*tanh_f(gg);
          float h  = sigm_f(go_)*tanh_f(cn);
          ((float*)&cn4)[jj] = cn;
          hp |= ((ull)f2bf(h)) << (16*jj);
        }
        *(float4*)&cst[ci0] = cn4;
        int tw = dir ? (511 - s) : s;
        st8u(hsb + (((size_t)dir*512 + tw)*32 + b)*512 + j0, hp);
      }
    }
    gbar2(flags, go, ++bar_t, bid, tid);
  }
}

// ---------------- head: out[b][t][c] = [hf|hb]·Whead^T + bhead
__global__ void k_head(const ushort* __restrict__ hsb, const float* __restrict__ Wh,
                       const float* __restrict__ bh, float* __restrict__ out)
{
  int wid = threadIdx.x >> 6, lane = threadIdx.x & 63;
  int r = blockIdx.x*4 + wid;
  int b = r >> 9, t = r & 511;
  float acc[7];
  #pragma unroll
  for (int c = 0; c < 7; c++) acc[c] = 0.f;
  const ushort* hf = hsb + (((size_t)t)*32 + b)*512;
  const ushort* hb = hsb + (((size_t)512 + t)*32 + b)*512;
  for (int k0 = 0; k0 < 512; k0 += 64) {
    int k = k0 + lane;
    float a = bf2f(hf[k]), bvv = bf2f(hb[k]);
    #pragma unroll
    for (int c = 0; c < 7; c++)
      acc[c] += a*Wh[c*1024 + k] + bvv*Wh[c*1024 + 512 + k];
  }
  #pragma unroll
  for (int c = 0; c < 7; c++) {
    float sres = acc[c];
    #pragma unroll
    for (int off = 32; off; off >>= 1) sres += __shfl_xor(sres, off);
    if (lane == c) out[((size_t)b*512 + t)*7 + c] = sres + bh[c];
  }
}

extern "C" void kernel_launch(void* const* d_in, const int* in_sizes, int n_in,
                              void* d_out, int out_size, void* d_ws, size_t ws_size,
                              hipStream_t stream) {
  (void)in_sizes; (void)n_in; (void)out_size;
  const float* x    = (const float*)d_in[0];
  const float* Wfih = (const float*)d_in[1];
  const float* Wfhh = (const float*)d_in[2];
  const float* bfv  = (const float*)d_in[3];
  const float* Wbih = (const float*)d_in[4];
  const float* Wbhh = (const float*)d_in[5];
  const float* bbv  = (const float*)d_in[6];
  const float* Wenc = (const float*)d_in[7];
  const float* benc = (const float*)d_in[8];
  const float* Wdec = (const float*)d_in[9];
  const float* bdec = (const float*)d_in[10];
  const float* v    = (const float*)d_in[11];
  const float* Whead= (const float*)d_in[12];
  const float* bhead= (const float*)d_in[13];
  float* out = (float*)d_out;
  char* ws = (char*)d_ws;

  if (ws_size < WS_BYTES) return;

  ushort* ep   = (ushort*)(ws + EPB);
  ushort* xb   = (ushort*)(ws + XBB);
  ushort* hsb  = (ushort*)(ws + HSB);
  ushort* wpk  = (ushort*)(ws + WPKB);
  ushort* wdp  = (ushort*)(ws + WDPB);
  float*  uctx = (float*)(ws + UCTXB);
  float*  Zb   = (float*)(ws + ZBB);
  float*  dec  = (float*)(ws + DECB);
  float*  cst  = (float*)(ws + CSTB);
  uint*   flags= (uint*)(ws + GSYB);
  uint*   go   = (uint*)(ws + GSYB + 16384);

  static int attr_set = 0;
  if (!attr_set) {
    hipFuncSetAttribute(reinterpret_cast<const void*>(k_loop),
                        hipFuncAttributeMaxDynamicSharedMemorySize, LDS_BYTES);
    attr_set = 1;
  }

  hipMemsetAsync(ws + CSTB, 0, (size_t)2*NB*HH*4, stream);
  hipMemsetAsync(ws + GSYB, 0, 32768, stream);

  hipLaunchKernelGGL(k_xcast, dim3(6144), dim3(256), 0, stream, x, xb);
  hipLaunchKernelGGL(k_encproj, dim3(8,8,32), dim3(256), 0, stream, x, Wenc, benc, ep);
  hipLaunchKernelGGL(k_wpack, dim3(4096), dim3(256), 0, stream, Wfih, Wfhh, Wbih, Wbhh, wpk);
  hipLaunchKernelGGL(k_wdpack, dim3(128), dim3(256), 0, stream, Wdec, wdp);

  void* args[] = {
    (void*)&hsb, (void*)&xb, (void*)&ep, (void*)&wpk, (void*)&wdp,
    (void*)&uctx, (void*)&Zb, (void*)&dec, (void*)&cst,
    (void*)&bdec, (void*)&v, (void*)&bfv, (void*)&bbv, (void*)&flags, (void*)&go
  };
  hipLaunchCooperativeKernel(reinterpret_cast<void*>(k_loop), dim3(256), dim3(512),
                             args, LDS_BYTES, stream);

  hipLaunchKernelGGL(k_head, dim3(4096), dim3(256), 0, stream, hsb, Whead, bhead, out);
}